// Round 16
// baseline (2105.000 us; speedup 1.0000x reference)
//
#include <hip/hip_runtime.h>
#include <hip/hip_fp16.h>

// B=2048, T=128, N=64, H=128
// inputs: 0 X(2048,128,64) 1 W_attn1(128,384) 2 b_attn1(128) 3 w_attn2(128)
//         4 b_attn2(1)[unused] 5 W_ih(512,64) 6 W_hh(512,128) 7 b_ih(512) 8 b_hh(512)
// output: (2048,128,128) f32
//
// R16 = R15 with 8 batches/block, 256 blocks (exactly 1 block/CU, ONE pass).
// Same 32 MFMA/wave/step now cover 8 of 16 tile rows (util 25%->50%); total
// MFMA, barriers, LDS traffic per CU halve. P2 tanh doubles per step but total
// is constant. P3 uses all 512 threads (wave w = batch w). px in regs (64 VGPR).
// ws (f32 units): Wt @0 | p1p @16384 | p4p @32768 | prexH @81920 (8388608, END)

typedef float f32x4 __attribute__((ext_vector_type(4)));
typedef _Float16 f16x8 __attribute__((ext_vector_type(8)));
typedef _Float16 f16x4 __attribute__((ext_vector_type(4)));

#define LOG2E 1.44269504088896340736f
__device__ __forceinline__ float rcpf(float x){ return __builtin_amdgcn_rcpf(x); }
__device__ __forceinline__ float fast_exp(float x){ return __builtin_exp2f(x * LOG2E); }
__device__ __forceinline__ float fast_tanh(float x){
  float e = __builtin_exp2f(x * (2.0f * LOG2E));
  return 1.0f - 2.0f * rcpf(e + 1.0f);
}
__device__ __forceinline__ float fast_sig(float x){
  float e = __builtin_exp2f(x * (-LOG2E));
  return rcpf(1.0f + e);
}
__device__ __forceinline__ float sx(float v, int m){ return __shfl_xor(v, m, 64); }

// ---- k0_wt: Wt[t][k] = W1x[k][t] (for k1) ----
__global__ __launch_bounds__(256) void k0_wt(const float* __restrict__ Wat, float* __restrict__ Wt){
  int idx = blockIdx.x*256 + threadIdx.x;   // 16384
  int t = idx >> 7, k = idx & 127;
  Wt[idx] = Wat[k*384 + 256 + t];
}
// ---- k0_p1p: frag pack of W1=[W1h|W1s]^T (256->128) for MFMA B.
__global__ __launch_bounds__(256) void k0_p1p(const float* __restrict__ Wat, _Float16* __restrict__ p1p){
  int idx = blockIdx.x*256 + threadIdx.x;   // 32768 = 8w x 8f x 64l x 8e
  int e = idx & 7, l = (idx>>3) & 63, f = (idx>>9) & 7, w = idx >> 12;
  int col = w*16 + (l & 15);                // attn unit (0..127)
  int c   = f*32 + ((l>>4)&3)*8 + e;        // contraction (0..255): [h|c]
  p1p[idx] = (_Float16)Wat[col*384 + c];
}
// ---- k0_p4p: frag pack of Wc=[Wih|Whh]^T (192->512); wave w -> tiles 4w..4w+3
__global__ __launch_bounds__(256) void k0_p4p(const float* __restrict__ Wih, const float* __restrict__ Whh,
                                              _Float16* __restrict__ p4p){
  int idx = blockIdx.x*256 + threadIdx.x;   // 98304 = 8w x 24fi x 64l x 8e
  int e = idx & 7, l = (idx>>3) & 63, r = idx >> 9;   // r in [0,192)
  int fi = r % 24, w = r / 24;
  int ti = fi / 6, ks = fi % 6;
  int g = (w*4 + ti)*16 + (l & 15);         // gate unit (0..511) = q*128+j
  int c = ks*32 + ((l>>4)&3)*8 + e;         // contraction (0..191): [xt|h]
  p4p[idx] = (_Float16)((c < 64) ? Wih[g*64 + c] : Whh[g*128 + (c-64)]);
}

// ---- k1: prex[b][n][k] = f16( sum_t X[b][t][n]*W1x[k][t] + b1[k] )  (R9-identical)
__global__ __launch_bounds__(256) void k1_prex(const float* __restrict__ X,
                                               const float* __restrict__ Wt,
                                               const float* __restrict__ b1,
                                               __half* __restrict__ prex){
  __shared__ float Xs[128][64];
  const int tid = threadIdx.x;
  const long b = blockIdx.x;
  {
    const float4* X4 = (const float4*)(X + b*8192);
    float4* Xs4 = (float4*)&Xs[0][0];
    #pragma unroll
    for (int i=0;i<8;i++) Xs4[tid + i*256] = X4[tid + i*256];
  }
  __syncthreads();
  const int nq = tid >> 4, kq = tid & 15;
  float acc[4][8];
  #pragma unroll
  for (int n=0;n<4;n++)
    #pragma unroll
    for (int k=0;k<8;k++) acc[n][k]=0.f;
  #pragma unroll 4
  for (int t=0;t<128;t++){
    float4 w0 = *(const float4*)(Wt + t*128 + kq*8);
    float4 w1 = *(const float4*)(Wt + t*128 + kq*8 + 4);
    float4 xv = *(const float4*)&Xs[t][nq*4];
    float wv[8] = {w0.x,w0.y,w0.z,w0.w,w1.x,w1.y,w1.z,w1.w};
    float xa[4] = {xv.x,xv.y,xv.z,xv.w};
    #pragma unroll
    for (int n=0;n<4;n++)
      #pragma unroll
      for (int k=0;k<8;k++) acc[n][k] = fmaf(xa[n], wv[k], acc[n][k]);
  }
  float4 bv0 = *(const float4*)(b1 + kq*8);
  float4 bv1 = *(const float4*)(b1 + kq*8 + 4);
  #pragma unroll
  for (int n=0;n<4;n++){
    __half* dst = prex + ((long)(b*64 + nq*4 + n))*128 + kq*8;
    union { __half2 h2[4]; uint4 u4; } pk;
    pk.h2[0] = __floats2half2_rn(acc[n][0]+bv0.x, acc[n][1]+bv0.y);
    pk.h2[1] = __floats2half2_rn(acc[n][2]+bv0.z, acc[n][3]+bv0.w);
    pk.h2[2] = __floats2half2_rn(acc[n][4]+bv1.x, acc[n][5]+bv1.y);
    pk.h2[3] = __floats2half2_rn(acc[n][6]+bv1.z, acc[n][7]+bv1.w);
    *(uint4*)dst = pk.u4;
  }
}

// ---- k2: 256 blocks x 512 threads, 8 batches/block, ONE pass ----
__global__ __launch_bounds__(512, 2)
void k2_lstm(const float* __restrict__ X,
             const _Float16* __restrict__ p1p,
             const _Float16* __restrict__ p4p,
             const float* __restrict__ w2,
             const float* __restrict__ bih,
             const float* __restrict__ bhh,
             const __half* __restrict__ prex,
             float* __restrict__ out)
{
  const int tid = threadIdx.x;
  const long b0 = (long)blockIdx.x * 8;
  const int w = tid >> 6, l = tid & 63;

  // A tiles, rows = batches 0..7 (rows 8..15 stay zero). Padded rows (2-way
  // bank conflicts only): A1 264 halfs/row, A4 200 halfs/row.
  __shared__ alignas(16) _Float16 A1[16*264];  // [h | c], K=256         8.25 KB
  __shared__ alignas(16) _Float16 A4[16*200];  // [xt | h], K=192        6.25 KB
  __shared__ float aa[8][128];       // attn pre-act (h,c part)          4 KB
  __shared__ float gp[8][512];       // gates                           16 KB
  __shared__ float epp[8][64][2];    // P2 partials                      4 KB
  // total ~38.5 KB

  for (int i = tid; i < 16*264; i += 512) A1[i] = (_Float16)0.f;
  for (int i = tid; i < 16*200; i += 512) A4[i] = (_Float16)0.f;

  // ---- weight fragments -> VGPRs (persist all 128 steps)
  f16x8 w1f[8];
  {
    const f16x8* p = (const f16x8*)p1p;
    #pragma unroll
    for (int f = 0; f < 8; ++f) w1f[f] = p[(w*8 + f)*64 + l];
  }
  f16x8 w4f[24];
  {
    const f16x8* p = (const f16x8*)p4p;
    #pragma unroll
    for (int f = 0; f < 24; ++f) w4f[f] = p[(w*24 + f)*64 + l];
  }

  // ---- px slice -> registers: wave w = batch w; lane: kq = l&31, ng = l>>5.
  // Lane covers rows n = ng*32 + i (i=0..31), quad kq.
  const int kq = l & 31, ng = l >> 5;
  f16x4 pxr[32];
  {
    const _Float16* pb = (const _Float16*)prex + ((b0 + w)*64 + ng*32)*128 + kq*4;
    #pragma unroll
    for (int i = 0; i < 32; ++i) pxr[i] = *(const f16x4*)(pb + i*128);
  }
  const f32x4 w2v = *(const f32x4*)(w2 + kq*4);

  // MFMA lane constants: arow = A-row this lane reads, ag = k-slot quarter
  const int arow = l & 15, ag = l >> 4;

  // P5 role: thread = (batches ob & ob+4, unit oj)
  const int ob = tid >> 7, oj = tid & 127;
  const float bl0 = bih[oj]       + bhh[oj];
  const float bl1 = bih[oj + 128] + bhh[oj + 128];
  const float bl2 = bih[oj + 256] + bhh[oj + 256];
  const float bl3 = bih[oj + 384] + bhh[oj + 384];
  float cre0 = 0.f, cre1 = 0.f;     // exact f32 c-states (batches ob, ob+4)

  // P3/X role: b = tid>>6 (= wave), n = tid&63
  float xreg = 0.f;

  __syncthreads();

  for (int t = 0; t < 128; ++t) {
    // X prefetch (used in P3): all 512 threads, (b=w, n=l)
    xreg = X[(b0 + w)*8192 + (long)t*64 + l];

    // ---------- P1 (MFMA): aa[8][128] = [h|c](8x256) @ W1; wave w -> cols w*16..+16
    {
      f32x4 acc = {0.f,0.f,0.f,0.f};
      const _Float16* Ab = A1 + arow*264 + ag*8;
      #pragma unroll
      for (int f = 0; f < 8; ++f) {
        f16x8 a = *(const f16x8*)(Ab + f*32);
        acc = __builtin_amdgcn_mfma_f32_16x16x32_f16(a, w1f[f], acc, 0, 0, 0);
      }
      if (l < 32) {   // D: col = l&15, row = (l>>4)*4 + v  (batches 0..7)
        int rb = (l >> 4) * 4;
        #pragma unroll
        for (int v = 0; v < 4; ++v) aa[rb + v][w*16 + (l & 15)] = acc[v];
      }
    }
    __syncthreads();

    // ---------- P2: e-partials; wave w = batch w; px in regs, tanh on VALU
    {
      f32x4 aq = *(const f32x4*)&aa[w][kq*4];
      #pragma unroll
      for (int i = 0; i < 32; ++i) {
        f16x4 p = pxr[i];
        float e = fmaf(fast_tanh((float)p[0] + aq.x), w2v.x,
                  fmaf(fast_tanh((float)p[1] + aq.y), w2v.y,
                  fmaf(fast_tanh((float)p[2] + aq.z), w2v.z,
                       fast_tanh((float)p[3] + aq.w) * w2v.w)));
        e += sx(e, 1);
        e += sx(e, 2);
        e += sx(e, 4);
        e += sx(e, 8);
        if ((kq & 15) == 0) epp[w][ng*32 + i][kq >> 4] = e;
      }
    }
    __syncthreads();

    // ---------- P3: softmax over n (wave w = batch w), x_tilde -> A4[b][n]
    {
      float e = epp[w][l][0] + epp[w][l][1];
      float mx = e;
      #pragma unroll
      for (int m = 32; m >= 1; m >>= 1) mx = fmaxf(mx, sx(mx, m));
      float p = fast_exp(e - mx);
      float sm = p;
      #pragma unroll
      for (int m = 32; m >= 1; m >>= 1) sm += sx(sm, m);
      float xtv = p * rcpf(sm) * xreg;
      A4[w*200 + l] = (_Float16)xtv;
    }
    __syncthreads();

    // ---------- P4 (MFMA): gates[8][512] = A4(8x192) @ Wc; wave w -> tiles 4w..4w+3
    {
      f32x4 c0 = {0.f,0.f,0.f,0.f}, c1 = c0, c2 = c0, c3 = c0;
      const _Float16* Ab = A4 + arow*200 + ag*8;
      #pragma unroll
      for (int ks = 0; ks < 6; ++ks) {
        f16x8 a = *(const f16x8*)(Ab + ks*32);
        c0 = __builtin_amdgcn_mfma_f32_16x16x32_f16(a, w4f[ks],      c0, 0, 0, 0);
        c1 = __builtin_amdgcn_mfma_f32_16x16x32_f16(a, w4f[6  + ks], c1, 0, 0, 0);
        c2 = __builtin_amdgcn_mfma_f32_16x16x32_f16(a, w4f[12 + ks], c2, 0, 0, 0);
        c3 = __builtin_amdgcn_mfma_f32_16x16x32_f16(a, w4f[18 + ks], c3, 0, 0, 0);
      }
      if (l < 32) {
        int rb = (l >> 4) * 4, col = l & 15;
        #pragma unroll
        for (int v = 0; v < 4; ++v) {
          gp[rb + v][(w*4 + 0)*16 + col] = c0[v];
          gp[rb + v][(w*4 + 1)*16 + col] = c1[v];
          gp[rb + v][(w*4 + 2)*16 + col] = c2[v];
          gp[rb + v][(w*4 + 3)*16 + col] = c3[v];
        }
      }
    }
    __syncthreads();

    // ---------- P5: pointwise LSTM x2 batches; c exact f32; publish f16 state
    {
      // batch ob
      float s0 = gp[ob][oj]       + bl0;
      float s1 = gp[ob][oj + 128] + bl1;
      float s2 = gp[ob][oj + 256] + bl2;
      float s3 = gp[ob][oj + 384] + bl3;
      float ig = fast_sig(s0), fg = fast_sig(s1);
      float gg = fast_tanh(s2), og = fast_sig(s3);
      cre0 = fmaf(fg, cre0, ig*gg);
      float hn0 = og * fast_tanh(cre0);
      // batch ob+4
      float u0 = gp[ob+4][oj]       + bl0;
      float u1 = gp[ob+4][oj + 128] + bl1;
      float u2 = gp[ob+4][oj + 256] + bl2;
      float u3 = gp[ob+4][oj + 384] + bl3;
      float ih = fast_sig(u0), fh = fast_sig(u1);
      float gh = fast_tanh(u2), oh = fast_sig(u3);
      cre1 = fmaf(fh, cre1, ih*gh);
      float hn1 = oh * fast_tanh(cre1);

      _Float16 h0 = (_Float16)hn0, h1 = (_Float16)hn1;
      A1[ob*264 + oj]           = h0;
      A1[ob*264 + 128 + oj]     = (_Float16)cre0;
      A4[ob*200 + 64 + oj]      = h0;
      A1[(ob+4)*264 + oj]       = h1;
      A1[(ob+4)*264 + 128 + oj] = (_Float16)cre1;
      A4[(ob+4)*200 + 64 + oj]  = h1;
      out[(b0+ob)*16384   + (long)t*128 + oj] = hn0;
      out[(b0+ob+4)*16384 + (long)t*128 + oj] = hn1;
    }
    __syncthreads();
  }
}

extern "C" void kernel_launch(void* const* d_in, const int* in_sizes, int n_in,
                              void* d_out, int out_size, void* d_ws, size_t ws_size,
                              hipStream_t stream) {
  const float* X   = (const float*)d_in[0];
  const float* Wat = (const float*)d_in[1];
  const float* b1  = (const float*)d_in[2];
  const float* w2  = (const float*)d_in[3];
  const float* Wih = (const float*)d_in[5];
  const float* Whh = (const float*)d_in[6];
  const float* bih = (const float*)d_in[7];
  const float* bhh = (const float*)d_in[8];
  float* out  = (float*)d_out;

  // FIXED layout: prex (16,777,216 halfs = 8,388,608 f32) at the END.
  float*    Wt   = (float*)d_ws;                 // [0, 16384) f32
  _Float16* p1p  = (_Float16*)(Wt + 16384);      // 32768 halfs
  _Float16* p4p  = (_Float16*)(Wt + 32768);      // 98304 halfs
  __half*   prexH= (__half*)(Wt + 81920);        // 16,777,216 halfs

  k0_wt  <<<64,  256, 0, stream>>>(Wat, Wt);
  k0_p1p <<<128, 256, 0, stream>>>(Wat, p1p);
  k0_p4p <<<384, 256, 0, stream>>>(Wih, Whh, p4p);
  k1_prex<<<2048,256, 0, stream>>>(X, Wt, b1, prexH);
  k2_lstm<<<256, 512, 0, stream>>>(X, p1p, p4p, w2, bih, bhh, prexH, out);
}